// Round 8
// baseline (286.392 us; speedup 1.0000x reference)
//
#include <hip/hip_runtime.h>

#define NN 100000
#define EE 500000
#define FIN 64
#define HH 128
#define BN_EPS 1e-5f
#define NB ((NN + 255) / 256)   // 391 scan blocks

typedef unsigned short u16;
typedef short bf16x8 __attribute__((ext_vector_type(8)));
typedef float f32x4 __attribute__((ext_vector_type(4)));

__device__ __forceinline__ u16 f2bf(float f) {
    unsigned int u = __float_as_uint(f);
    u = (u + 0x7FFFu + ((u >> 16) & 1u)) >> 16;   // round-to-nearest-even
    return (u16)u;
}
__device__ __forceinline__ float bf2f(u16 u) {
    return __uint_as_float((unsigned int)u << 16);
}

// ---------------- x -> bf16 convert + zero deg (replaces hipMemsetAsync) ----------------
// 8 floats per thread: NN*FIN/8 = 800000 threads; threads < NN also zero deg.

__global__ __launch_bounds__(256) void x2bf_zero_kernel(const float* __restrict__ x,
                                                        u16* __restrict__ xb,
                                                        int* __restrict__ deg) {
    int i = blockIdx.x * 256 + threadIdx.x;
    if (i < NN) deg[i] = 0;
    if (i >= NN * FIN / 8) return;
    float4 f0 = ((const float4*)x)[i * 2];
    float4 f1 = ((const float4*)x)[i * 2 + 1];
    uint4 o;
    o.x = (unsigned)f2bf(f0.x) | ((unsigned)f2bf(f0.y) << 16);
    o.y = (unsigned)f2bf(f0.z) | ((unsigned)f2bf(f0.w) << 16);
    o.z = (unsigned)f2bf(f1.x) | ((unsigned)f2bf(f1.y) << 16);
    o.w = (unsigned)f2bf(f1.z) | ((unsigned)f2bf(f1.w) << 16);
    ((uint4*)xb)[i] = o;
}

// ---------------- all three W [K][HH] fp32 -> Wt [HH][K] bf16 ----------------

__global__ __launch_bounds__(256) void wconv_all_kernel(const float* __restrict__ W1,
                                                        const float* __restrict__ W2,
                                                        const float* __restrict__ W3,
                                                        u16* __restrict__ wt1,
                                                        u16* __restrict__ wt2,
                                                        u16* __restrict__ wt3) {
    int i = blockIdx.x * 256 + threadIdx.x;
    if (i < HH * FIN) {
        int n = i / FIN, k = i - n * FIN;
        wt1[i] = f2bf(W1[(size_t)k * HH + n]);
    } else if (i < HH * FIN + HH * HH) {
        int j = i - HH * FIN;
        int n = j / HH, k = j - n * HH;
        wt2[j] = f2bf(W2[(size_t)k * HH + n]);
    } else if (i < HH * FIN + 2 * HH * HH) {
        int j = i - HH * FIN - HH * HH;
        int n = j / HH, k = j - n * HH;
        wt3[j] = f2bf(W3[(size_t)k * HH + n]);
    }
}

// ---------------- CSR build ----------------

__global__ __launch_bounds__(256) void hist_kernel(const int* __restrict__ dst,
                                                   int* __restrict__ deg) {
    int e = blockIdx.x * 256 + threadIdx.x;
    if (e < EE) atomicAdd(&deg[dst[e]], 1);
}

// scan1 + dinv fused
__global__ __launch_bounds__(256) void scan1_kernel(const int* __restrict__ deg,
                                                    int* __restrict__ rowstart,
                                                    int* __restrict__ blksum,
                                                    float* __restrict__ dinv) {
    __shared__ int s[256];
    int t = threadIdx.x;
    int i = blockIdx.x * 256 + t;
    int v = (i < NN) ? deg[i] : 0;
    if (i < NN) dinv[i] = rsqrtf((float)v + 1.0f);
    s[t] = v;
    __syncthreads();
    #pragma unroll
    for (int off = 1; off < 256; off <<= 1) {
        int add = (t >= off) ? s[t - off] : 0;
        __syncthreads();
        s[t] += add;
        __syncthreads();
    }
    if (i < NN) rowstart[i] = s[t] - v;
    if (t == 255) blksum[blockIdx.x] = s[255];
}

__global__ __launch_bounds__(512) void scan2_kernel(int* __restrict__ blksum) {
    __shared__ int s[512];
    int t = threadIdx.x;
    int v = (t < NB) ? blksum[t] : 0;
    s[t] = v;
    __syncthreads();
    #pragma unroll
    for (int off = 1; off < 512; off <<= 1) {
        int add = (t >= off) ? s[t - off] : 0;
        __syncthreads();
        s[t] += add;
        __syncthreads();
    }
    if (t < NB) blksum[t] = s[t] - v;
}

__global__ __launch_bounds__(256) void scan3_kernel(int* __restrict__ rowstart,
                                                    const int* __restrict__ blksum,
                                                    int* __restrict__ cursor) {
    int i = blockIdx.x * 256 + threadIdx.x;
    if (i < NN) {
        int r = rowstart[i] + blksum[i >> 8];
        rowstart[i] = r;
        cursor[i] = r;
    }
    if (i == 0) rowstart[NN] = EE;
}

__global__ __launch_bounds__(256) void fill_kernel(const int* __restrict__ src,
                                                   const int* __restrict__ dst,
                                                   const float* __restrict__ dinv,
                                                   int* __restrict__ cursor,
                                                   int2* __restrict__ csr) {
    int e = blockIdx.x * 256 + threadIdx.x;
    if (e >= EE) return;
    int s = src[e];
    int d = dst[e];
    float nm = dinv[s] * dinv[d];
    int pos = atomicAdd(&cursor[d], 1);
    csr[pos] = make_int2(s, __float_as_int(nm));
}

// ---------------- fused layer: gather-agg (64 rows -> LDS) + MFMA GEMM + BN + ReLU ----------------
// Phase 1: aggregate 64 rows of xin into swizzled bf16 LDS tile (fp32 accum).
// Phase 2: C[64 x 128] = Asm @ Wt^T via mfma_16x16x32_bf16, BN+relu epilogue.
// FUSE_Z: emit z[row] = dot(relu(bn(C))+res, W4) instead of storing C.

template<int K, bool FUSE_Z>
__global__ __launch_bounds__(256) void fused_layer(const u16* __restrict__ xin,
                                                   const int2* __restrict__ csr,
                                                   const int* __restrict__ rowstart,
                                                   const float* __restrict__ dinv,
                                                   const u16* __restrict__ Wt,
                                                   const float* __restrict__ bias,
                                                   const float* __restrict__ g,
                                                   const float* __restrict__ be,
                                                   const float* __restrict__ m,
                                                   const float* __restrict__ v,
                                                   const u16* __restrict__ res,
                                                   u16* __restrict__ out,
                                                   const float* __restrict__ W4,
                                                   float* __restrict__ z) {
    __shared__ u16 Asm[64 * K];   // row stride 2K bytes, byte ^= (row&7)<<4

    int tid = threadIdx.x;
    int blk0 = blockIdx.x * 64;

    // ---- phase 1: gather aggregation into LDS
    if constexpr (K == 128) {
        int grp = tid >> 5, lane = tid & 31;       // 8 groups x 32 lanes
        const ushort4* xp = (const ushort4*)xin;   // row = 32 x ushort4
        #pragma unroll
        for (int i = 0; i < 8; i++) {
            int lr = grp * 8 + i;
            int row = blk0 + lr;
            float a0 = 0.f, a1 = 0.f, a2 = 0.f, a3 = 0.f;
            if (row < NN) {
                float sn = dinv[row];
                sn *= sn;
                ushort4 xv = xp[(size_t)row * 32 + lane];
                a0 = bf2f(xv.x) * sn; a1 = bf2f(xv.y) * sn;
                a2 = bf2f(xv.z) * sn; a3 = bf2f(xv.w) * sn;
                int e0 = rowstart[row], e1 = rowstart[row + 1];
                int e = e0;
                for (; e + 4 <= e1; e += 4) {
                    int2 d0 = csr[e + 0];
                    int2 d1 = csr[e + 1];
                    int2 d2 = csr[e + 2];
                    int2 d3 = csr[e + 3];
                    ushort4 s0 = xp[(size_t)d0.x * 32 + lane];
                    ushort4 s1 = xp[(size_t)d1.x * 32 + lane];
                    ushort4 s2 = xp[(size_t)d2.x * 32 + lane];
                    ushort4 s3 = xp[(size_t)d3.x * 32 + lane];
                    float w0 = __int_as_float(d0.y), w1 = __int_as_float(d1.y);
                    float w2 = __int_as_float(d2.y), w3 = __int_as_float(d3.y);
                    a0 += bf2f(s0.x) * w0; a1 += bf2f(s0.y) * w0; a2 += bf2f(s0.z) * w0; a3 += bf2f(s0.w) * w0;
                    a0 += bf2f(s1.x) * w1; a1 += bf2f(s1.y) * w1; a2 += bf2f(s1.z) * w1; a3 += bf2f(s1.w) * w1;
                    a0 += bf2f(s2.x) * w2; a1 += bf2f(s2.y) * w2; a2 += bf2f(s2.z) * w2; a3 += bf2f(s2.w) * w2;
                    a0 += bf2f(s3.x) * w3; a1 += bf2f(s3.y) * w3; a2 += bf2f(s3.z) * w3; a3 += bf2f(s3.w) * w3;
                }
                for (; e < e1; e++) {
                    int2 ed = csr[e];
                    float w = __int_as_float(ed.y);
                    ushort4 xs = xp[(size_t)ed.x * 32 + lane];
                    a0 += bf2f(xs.x) * w; a1 += bf2f(xs.y) * w;
                    a2 += bf2f(xs.z) * w; a3 += bf2f(xs.w) * w;
                }
            }
            uint2 o;
            o.x = (unsigned)f2bf(a0) | ((unsigned)f2bf(a1) << 16);
            o.y = (unsigned)f2bf(a2) | ((unsigned)f2bf(a3) << 16);
            int byte = (lr * 256 + lane * 8) ^ ((lr & 7) << 4);
            *(uint2*)((char*)Asm + byte) = o;
        }
    } else {   // K == 64
        int grp = tid >> 4, lane = tid & 15;       // 16 groups x 16 lanes
        const ushort4* xp = (const ushort4*)xin;   // row = 16 x ushort4
        #pragma unroll
        for (int i = 0; i < 4; i++) {
            int lr = grp * 4 + i;
            int row = blk0 + lr;
            float a0 = 0.f, a1 = 0.f, a2 = 0.f, a3 = 0.f;
            if (row < NN) {
                float sn = dinv[row];
                sn *= sn;
                ushort4 xv = xp[(size_t)row * 16 + lane];
                a0 = bf2f(xv.x) * sn; a1 = bf2f(xv.y) * sn;
                a2 = bf2f(xv.z) * sn; a3 = bf2f(xv.w) * sn;
                int e0 = rowstart[row], e1 = rowstart[row + 1];
                int e = e0;
                for (; e + 4 <= e1; e += 4) {
                    int2 d0 = csr[e + 0];
                    int2 d1 = csr[e + 1];
                    int2 d2 = csr[e + 2];
                    int2 d3 = csr[e + 3];
                    ushort4 s0 = xp[(size_t)d0.x * 16 + lane];
                    ushort4 s1 = xp[(size_t)d1.x * 16 + lane];
                    ushort4 s2 = xp[(size_t)d2.x * 16 + lane];
                    ushort4 s3 = xp[(size_t)d3.x * 16 + lane];
                    float w0 = __int_as_float(d0.y), w1 = __int_as_float(d1.y);
                    float w2 = __int_as_float(d2.y), w3 = __int_as_float(d3.y);
                    a0 += bf2f(s0.x) * w0; a1 += bf2f(s0.y) * w0; a2 += bf2f(s0.z) * w0; a3 += bf2f(s0.w) * w0;
                    a0 += bf2f(s1.x) * w1; a1 += bf2f(s1.y) * w1; a2 += bf2f(s1.z) * w1; a3 += bf2f(s1.w) * w1;
                    a0 += bf2f(s2.x) * w2; a1 += bf2f(s2.y) * w2; a2 += bf2f(s2.z) * w2; a3 += bf2f(s2.w) * w2;
                    a0 += bf2f(s3.x) * w3; a1 += bf2f(s3.y) * w3; a2 += bf2f(s3.z) * w3; a3 += bf2f(s3.w) * w3;
                }
                for (; e < e1; e++) {
                    int2 ed = csr[e];
                    float w = __int_as_float(ed.y);
                    ushort4 xs = xp[(size_t)ed.x * 16 + lane];
                    a0 += bf2f(xs.x) * w; a1 += bf2f(xs.y) * w;
                    a2 += bf2f(xs.z) * w; a3 += bf2f(xs.w) * w;
                }
            }
            uint2 o;
            o.x = (unsigned)f2bf(a0) | ((unsigned)f2bf(a1) << 16);
            o.y = (unsigned)f2bf(a2) | ((unsigned)f2bf(a3) << 16);
            int byte = (lr * 128 + lane * 8) ^ ((lr & 7) << 4);
            *(uint2*)((char*)Asm + byte) = o;
        }
    }
    __syncthreads();

    // ---- phase 2: MFMA
    int wave = tid >> 6;
    int lane = tid & 63;
    int lrow = lane & 15;
    int kgrp = lane >> 4;
    int r0 = blk0 + wave * 16;

    f32x4 acc[8];
    #pragma unroll
    for (int ct = 0; ct < 8; ct++) acc[ct] = (f32x4){0.f, 0.f, 0.f, 0.f};

    #pragma unroll
    for (int kc = 0; kc < K / 32; kc++) {
        int abyte = ((wave * 16 + lrow) * (2 * K) + kc * 64 + kgrp * 16) ^ ((lrow & 7) << 4);
        bf16x8 afr = *(bf16x8*)((char*)Asm + abyte);
        bf16x8 bfr[8];
        #pragma unroll
        for (int ct = 0; ct < 8; ct++)
            bfr[ct] = *(const bf16x8*)&Wt[(size_t)(ct * 16 + lrow) * K + kc * 32 + kgrp * 8];
        #pragma unroll
        for (int ct = 0; ct < 8; ct++)
            acc[ct] = __builtin_amdgcn_mfma_f32_16x16x32_bf16(afr, bfr[ct], acc[ct], 0, 0, 0);
    }

    float sc[8], sh[8];
    #pragma unroll
    for (int ct = 0; ct < 8; ct++) {
        int col = ct * 16 + lrow;
        float s = g[col] * rsqrtf(v[col] + BN_EPS);
        sc[ct] = s;
        sh[ct] = (bias[col] - m[col]) * s + be[col];
    }

    int rbase = kgrp * 4;   // C layout: row = r0 + rbase + r, col = ct*16 + lrow
    if constexpr (!FUSE_Z) {
        #pragma unroll
        for (int r = 0; r < 4; r++) {
            int row = r0 + rbase + r;
            if (row >= NN) continue;
            #pragma unroll
            for (int ct = 0; ct < 8; ct++) {
                float val = acc[ct][r] * sc[ct] + sh[ct];
                val = fmaxf(val, 0.0f);
                if (res) val += bf2f(res[(size_t)row * HH + ct * 16 + lrow]);
                out[(size_t)row * HH + ct * 16 + lrow] = f2bf(val);
            }
        }
    } else {
        float w4[8];
        #pragma unroll
        for (int ct = 0; ct < 8; ct++) w4[ct] = W4[ct * 16 + lrow];
        #pragma unroll
        for (int r = 0; r < 4; r++) {
            int row = r0 + rbase + r;
            float part = 0.0f;
            if (row < NN) {
                #pragma unroll
                for (int ct = 0; ct < 8; ct++) {
                    float val = acc[ct][r] * sc[ct] + sh[ct];
                    val = fmaxf(val, 0.0f);
                    val += bf2f(res[(size_t)row * HH + ct * 16 + lrow]);
                    part += val * w4[ct];
                }
            }
            #pragma unroll
            for (int off = 1; off < 16; off <<= 1)
                part += __shfl_xor(part, off, 16);
            if (lrow == 0 && row < NN) z[row] = part;
        }
    }
}

// ---------------- final: out[i] = b4 + z[i]*dinv^2 + sum z[src]*w ----------------

__global__ __launch_bounds__(256) void final_kernel(const float* __restrict__ z,
                                                    const int2* __restrict__ csr,
                                                    const int* __restrict__ rowstart,
                                                    const float* __restrict__ dinv,
                                                    const float* __restrict__ b4,
                                                    float* __restrict__ out) {
    int i = blockIdx.x * 256 + threadIdx.x;
    if (i >= NN) return;
    float acc = z[i] * dinv[i] * dinv[i] + b4[0];
    int e0 = rowstart[i], e1 = rowstart[i + 1];
    int e = e0;
    for (; e + 4 <= e1; e += 4) {
        int2 d0 = csr[e + 0];
        int2 d1 = csr[e + 1];
        int2 d2 = csr[e + 2];
        int2 d3 = csr[e + 3];
        float z0 = z[d0.x], z1 = z[d1.x], z2 = z[d2.x], z3 = z[d3.x];
        acc += z0 * __int_as_float(d0.y) + z1 * __int_as_float(d1.y)
             + z2 * __int_as_float(d2.y) + z3 * __int_as_float(d3.y);
    }
    for (; e < e1; e++) {
        int2 ed = csr[e];
        acc += z[ed.x] * __int_as_float(ed.y);
    }
    out[i] = acc;
}

// ---------------- launch ----------------

extern "C" void kernel_launch(void* const* d_in, const int* in_sizes, int n_in,
                              void* d_out, int out_size, void* d_ws, size_t ws_size,
                              hipStream_t stream) {
    const float* x   = (const float*)d_in[0];
    const int*   ei  = (const int*)d_in[1];
    const int*   src = ei;
    const int*   dst = ei + EE;
    const float* W1 = (const float*)d_in[2];
    const float* b1 = (const float*)d_in[3];
    const float* g1 = (const float*)d_in[4];
    const float* be1 = (const float*)d_in[5];
    const float* m1 = (const float*)d_in[6];
    const float* v1 = (const float*)d_in[7];
    const float* W2 = (const float*)d_in[8];
    const float* b2 = (const float*)d_in[9];
    const float* g2 = (const float*)d_in[10];
    const float* be2 = (const float*)d_in[11];
    const float* m2 = (const float*)d_in[12];
    const float* v2 = (const float*)d_in[13];
    const float* W3 = (const float*)d_in[14];
    const float* b3 = (const float*)d_in[15];
    const float* g3 = (const float*)d_in[16];
    const float* be3 = (const float*)d_in[17];
    const float* m3 = (const float*)d_in[18];
    const float* v3 = (const float*)d_in[19];
    const float* W4 = (const float*)d_in[20];
    const float* b4 = (const float*)d_in[21];

    char* wp = (char*)d_ws;
    int*   deg      = (int*)wp;                      wp += (size_t)NN * 4;
    int*   blksum   = (int*)wp;                      wp += 512 * 4;
    int*   rowstart = (int*)wp;                      wp += (size_t)(NN + 1) * 4;
    int*   cursor   = (int*)wp;                      wp += (size_t)NN * 4;
    float* dinv     = (float*)wp;                    wp += (size_t)NN * 4;
    int2*  csr      = (int2*)wp;                     wp += (size_t)EE * 8;
    float* z        = (float*)wp;                    wp += (size_t)NN * 4;
    u16*   wt1      = (u16*)wp;                      wp += (size_t)HH * FIN * 2;
    u16*   wt2      = (u16*)wp;                      wp += (size_t)HH * HH * 2;
    u16*   wt3      = (u16*)wp;                      wp += (size_t)HH * HH * 2;
    u16*   xb       = (u16*)wp;                      wp += (size_t)NN * FIN * 2;
    u16*   x1       = (u16*)wp;                      wp += (size_t)NN * HH * 2;
    u16*   x2       = (u16*)wp;                      wp += (size_t)NN * HH * 2;

    float* outp = (float*)d_out;

    // ---- setup: conversions + CSR build (no hipMemsetAsync — x2bf_zero zeroes deg)
    x2bf_zero_kernel<<<(NN * FIN / 8 + 255) / 256, 256, 0, stream>>>(x, xb, deg);
    wconv_all_kernel<<<(HH * FIN + 2 * HH * HH + 255) / 256, 256, 0, stream>>>(
        W1, W2, W3, wt1, wt2, wt3);
    hist_kernel<<<(EE + 255) / 256, 256, 0, stream>>>(dst, deg);
    scan1_kernel<<<NB, 256, 0, stream>>>(deg, rowstart, blksum, dinv);
    scan2_kernel<<<1, 512, 0, stream>>>(blksum);
    scan3_kernel<<<NB, 256, 0, stream>>>(rowstart, blksum, cursor);
    fill_kernel<<<(EE + 255) / 256, 256, 0, stream>>>(src, dst, dinv, cursor, csr);

    // ---- layer 1: fused agg(xb) + GEMM 64->128 + BN + ReLU -> x1
    fused_layer<FIN, false><<<(NN + 63) / 64, 256, 0, stream>>>(
        xb, csr, rowstart, dinv, wt1, b1, g1, be1, m1, v1, nullptr, x1, nullptr, nullptr);

    // ---- layer 2: fused agg(x1) + GEMM 128->128 + BN + ReLU -> x2
    fused_layer<HH, false><<<(NN + 63) / 64, 256, 0, stream>>>(
        x1, csr, rowstart, dinv, wt2, b2, g2, be2, m2, v2, nullptr, x2, nullptr, nullptr);

    // ---- layer 3: fused agg(x2) + GEMM + BN + ReLU + residual(x1) + GEMV(W4) -> z
    fused_layer<HH, true><<<(NN + 63) / 64, 256, 0, stream>>>(
        x2, csr, rowstart, dinv, wt3, b3, g3, be3, m3, v3, x1, nullptr, W4, z);

    // ---- final aggregation of scalars
    final_kernel<<<(NN + 255) / 256, 256, 0, stream>>>(z, csr, rowstart, dinv, b4, outp);
}

// Round 9
// 260.007 us; speedup vs baseline: 1.1015x; 1.1015x over previous
//
#include <hip/hip_runtime.h>

#define NN 100000
#define EE 500000
#define FIN 64
#define HH 128
#define BN_EPS 1e-5f
#define NB ((NN + 255) / 256)   // 391 scan blocks

typedef unsigned short u16;
typedef short bf16x8 __attribute__((ext_vector_type(8)));
typedef float f32x4 __attribute__((ext_vector_type(4)));

__device__ __forceinline__ u16 f2bf(float f) {
    unsigned int u = __float_as_uint(f);
    u = (u + 0x7FFFu + ((u >> 16) & 1u)) >> 16;   // round-to-nearest-even
    return (u16)u;
}
__device__ __forceinline__ float bf2f(u16 u) {
    return __uint_as_float((unsigned int)u << 16);
}

// ---------------- x -> bf16 convert + zero deg (replaces hipMemsetAsync) ----------------

__global__ __launch_bounds__(256) void x2bf_zero_kernel(const float* __restrict__ x,
                                                        u16* __restrict__ xb,
                                                        int* __restrict__ deg) {
    int i = blockIdx.x * 256 + threadIdx.x;
    if (i < NN) deg[i] = 0;
    if (i >= NN * FIN / 8) return;
    float4 f0 = ((const float4*)x)[i * 2];
    float4 f1 = ((const float4*)x)[i * 2 + 1];
    uint4 o;
    o.x = (unsigned)f2bf(f0.x) | ((unsigned)f2bf(f0.y) << 16);
    o.y = (unsigned)f2bf(f0.z) | ((unsigned)f2bf(f0.w) << 16);
    o.z = (unsigned)f2bf(f1.x) | ((unsigned)f2bf(f1.y) << 16);
    o.w = (unsigned)f2bf(f1.z) | ((unsigned)f2bf(f1.w) << 16);
    ((uint4*)xb)[i] = o;
}

// ---------------- all three W [K][HH] fp32 -> Wt [HH][K] bf16 ----------------

__global__ __launch_bounds__(256) void wconv_all_kernel(const float* __restrict__ W1,
                                                        const float* __restrict__ W2,
                                                        const float* __restrict__ W3,
                                                        u16* __restrict__ wt1,
                                                        u16* __restrict__ wt2,
                                                        u16* __restrict__ wt3) {
    int i = blockIdx.x * 256 + threadIdx.x;
    if (i < HH * FIN) {
        int n = i / FIN, k = i - n * FIN;
        wt1[i] = f2bf(W1[(size_t)k * HH + n]);
    } else if (i < HH * FIN + HH * HH) {
        int j = i - HH * FIN;
        int n = j / HH, k = j - n * HH;
        wt2[j] = f2bf(W2[(size_t)k * HH + n]);
    } else if (i < HH * FIN + 2 * HH * HH) {
        int j = i - HH * FIN - HH * HH;
        int n = j / HH, k = j - n * HH;
        wt3[j] = f2bf(W3[(size_t)k * HH + n]);
    }
}

// ---------------- CSR build ----------------

__global__ __launch_bounds__(256) void hist_kernel(const int* __restrict__ dst,
                                                   int* __restrict__ deg) {
    int e = blockIdx.x * 256 + threadIdx.x;
    if (e < EE) atomicAdd(&deg[dst[e]], 1);
}

// scan1 + dinv fused
__global__ __launch_bounds__(256) void scan1_kernel(const int* __restrict__ deg,
                                                    int* __restrict__ rowstart,
                                                    int* __restrict__ blksum,
                                                    float* __restrict__ dinv) {
    __shared__ int s[256];
    int t = threadIdx.x;
    int i = blockIdx.x * 256 + t;
    int v = (i < NN) ? deg[i] : 0;
    if (i < NN) dinv[i] = rsqrtf((float)v + 1.0f);
    s[t] = v;
    __syncthreads();
    #pragma unroll
    for (int off = 1; off < 256; off <<= 1) {
        int add = (t >= off) ? s[t - off] : 0;
        __syncthreads();
        s[t] += add;
        __syncthreads();
    }
    if (i < NN) rowstart[i] = s[t] - v;
    if (t == 255) blksum[blockIdx.x] = s[255];
}

__global__ __launch_bounds__(512) void scan2_kernel(int* __restrict__ blksum) {
    __shared__ int s[512];
    int t = threadIdx.x;
    int v = (t < NB) ? blksum[t] : 0;
    s[t] = v;
    __syncthreads();
    #pragma unroll
    for (int off = 1; off < 512; off <<= 1) {
        int add = (t >= off) ? s[t - off] : 0;
        __syncthreads();
        s[t] += add;
        __syncthreads();
    }
    if (t < NB) blksum[t] = s[t] - v;
}

__global__ __launch_bounds__(256) void scan3_kernel(int* __restrict__ rowstart,
                                                    const int* __restrict__ blksum,
                                                    int* __restrict__ cursor) {
    int i = blockIdx.x * 256 + threadIdx.x;
    if (i < NN) {
        int r = rowstart[i] + blksum[i >> 8];
        rowstart[i] = r;
        cursor[i] = r;
    }
    if (i == 0) rowstart[NN] = EE;
}

__global__ __launch_bounds__(256) void fill_kernel(const int* __restrict__ src,
                                                   const int* __restrict__ dst,
                                                   const float* __restrict__ dinv,
                                                   int* __restrict__ cursor,
                                                   int2* __restrict__ csr) {
    int e = blockIdx.x * 256 + threadIdx.x;
    if (e >= EE) return;
    int s = src[e];
    int d = dst[e];
    float nm = dinv[s] * dinv[d];
    int pos = atomicAdd(&cursor[d], 1);
    csr[pos] = make_int2(s, __float_as_int(nm));
}

// ---------------- gather aggregation (bf16 in/out, fp32 accumulate) ----------------
// latency-oriented: sub-wave per node + edge loop unrolled x4 (batched loads)

__global__ __launch_bounds__(256) void agg128_kernel(const u16* __restrict__ x,
                                                     const int2* __restrict__ csr,
                                                     const int* __restrict__ rowstart,
                                                     const float* __restrict__ dinv,
                                                     u16* __restrict__ out) {
    int gid = blockIdx.x * 8 + (threadIdx.x >> 5);
    int lane = threadIdx.x & 31;
    if (gid >= NN) return;
    float sn = dinv[gid];
    sn *= sn;
    const ushort4* xp = (const ushort4*)x;   // row = 32 x ushort4
    ushort4 xv = xp[(size_t)gid * 32 + lane];
    float a0 = bf2f(xv.x) * sn, a1 = bf2f(xv.y) * sn;
    float a2 = bf2f(xv.z) * sn, a3 = bf2f(xv.w) * sn;
    int e0 = rowstart[gid], e1 = rowstart[gid + 1];
    int e = e0;
    for (; e + 4 <= e1; e += 4) {
        int2 d0 = csr[e + 0];
        int2 d1 = csr[e + 1];
        int2 d2 = csr[e + 2];
        int2 d3 = csr[e + 3];
        ushort4 s0 = xp[(size_t)d0.x * 32 + lane];
        ushort4 s1 = xp[(size_t)d1.x * 32 + lane];
        ushort4 s2 = xp[(size_t)d2.x * 32 + lane];
        ushort4 s3 = xp[(size_t)d3.x * 32 + lane];
        float w0 = __int_as_float(d0.y), w1 = __int_as_float(d1.y);
        float w2 = __int_as_float(d2.y), w3 = __int_as_float(d3.y);
        a0 += bf2f(s0.x) * w0; a1 += bf2f(s0.y) * w0; a2 += bf2f(s0.z) * w0; a3 += bf2f(s0.w) * w0;
        a0 += bf2f(s1.x) * w1; a1 += bf2f(s1.y) * w1; a2 += bf2f(s1.z) * w1; a3 += bf2f(s1.w) * w1;
        a0 += bf2f(s2.x) * w2; a1 += bf2f(s2.y) * w2; a2 += bf2f(s2.z) * w2; a3 += bf2f(s2.w) * w2;
        a0 += bf2f(s3.x) * w3; a1 += bf2f(s3.y) * w3; a2 += bf2f(s3.z) * w3; a3 += bf2f(s3.w) * w3;
    }
    for (; e < e1; e++) {
        int2 ed = csr[e];
        float w = __int_as_float(ed.y);
        ushort4 xs = xp[(size_t)ed.x * 32 + lane];
        a0 += bf2f(xs.x) * w; a1 += bf2f(xs.y) * w;
        a2 += bf2f(xs.z) * w; a3 += bf2f(xs.w) * w;
    }
    uint2 o;
    o.x = (unsigned)f2bf(a0) | ((unsigned)f2bf(a1) << 16);
    o.y = (unsigned)f2bf(a2) | ((unsigned)f2bf(a3) << 16);
    ((uint2*)out)[(size_t)gid * 32 + lane] = o;
}

__global__ __launch_bounds__(256) void agg64_kernel(const u16* __restrict__ x,
                                                    const int2* __restrict__ csr,
                                                    const int* __restrict__ rowstart,
                                                    const float* __restrict__ dinv,
                                                    u16* __restrict__ out) {
    int gid = blockIdx.x * 16 + (threadIdx.x >> 4);
    int lane = threadIdx.x & 15;
    if (gid >= NN) return;
    float sn = dinv[gid];
    sn *= sn;
    const ushort4* xp = (const ushort4*)x;   // row = 16 x ushort4
    ushort4 xv = xp[(size_t)gid * 16 + lane];
    float a0 = bf2f(xv.x) * sn, a1 = bf2f(xv.y) * sn;
    float a2 = bf2f(xv.z) * sn, a3 = bf2f(xv.w) * sn;
    int e0 = rowstart[gid], e1 = rowstart[gid + 1];
    int e = e0;
    for (; e + 4 <= e1; e += 4) {
        int2 d0 = csr[e + 0];
        int2 d1 = csr[e + 1];
        int2 d2 = csr[e + 2];
        int2 d3 = csr[e + 3];
        ushort4 s0 = xp[(size_t)d0.x * 16 + lane];
        ushort4 s1 = xp[(size_t)d1.x * 16 + lane];
        ushort4 s2 = xp[(size_t)d2.x * 16 + lane];
        ushort4 s3 = xp[(size_t)d3.x * 16 + lane];
        float w0 = __int_as_float(d0.y), w1 = __int_as_float(d1.y);
        float w2 = __int_as_float(d2.y), w3 = __int_as_float(d3.y);
        a0 += bf2f(s0.x) * w0; a1 += bf2f(s0.y) * w0; a2 += bf2f(s0.z) * w0; a3 += bf2f(s0.w) * w0;
        a0 += bf2f(s1.x) * w1; a1 += bf2f(s1.y) * w1; a2 += bf2f(s1.z) * w1; a3 += bf2f(s1.w) * w1;
        a0 += bf2f(s2.x) * w2; a1 += bf2f(s2.y) * w2; a2 += bf2f(s2.z) * w2; a3 += bf2f(s2.w) * w2;
        a0 += bf2f(s3.x) * w3; a1 += bf2f(s3.y) * w3; a2 += bf2f(s3.z) * w3; a3 += bf2f(s3.w) * w3;
    }
    for (; e < e1; e++) {
        int2 ed = csr[e];
        float w = __int_as_float(ed.y);
        ushort4 xs = xp[(size_t)ed.x * 16 + lane];
        a0 += bf2f(xs.x) * w; a1 += bf2f(xs.y) * w;
        a2 += bf2f(xs.z) * w; a3 += bf2f(xs.w) * w;
    }
    uint2 o;
    o.x = (unsigned)f2bf(a0) | ((unsigned)f2bf(a1) << 16);
    o.y = (unsigned)f2bf(a2) | ((unsigned)f2bf(a3) << 16);
    ((uint2*)out)[(size_t)gid * 16 + lane] = o;
}

// ---------------- MFMA GEMM + bias + BN(eval) + ReLU (+ residual) ----------------
// No LDS, no barriers. B-fragments loaded from pre-converted Wt[HH][K] bf16 (L2-hot).
// Block = 256 thr = 4 waves; each wave owns 16 rows (BM=64). grid = ceil(N/64).
// FUSE_Z: z[row] = dot(relu(bn(C))+res, W4) via 16-lane reduce, no C store.

template<int K, bool FUSE_Z>
__global__ __launch_bounds__(256) void gemm_bn_relu(const u16* __restrict__ A,
                                                    const u16* __restrict__ Wt,
                                                    const float* __restrict__ bias,
                                                    const float* __restrict__ g,
                                                    const float* __restrict__ be,
                                                    const float* __restrict__ m,
                                                    const float* __restrict__ v,
                                                    const u16* __restrict__ res,
                                                    u16* __restrict__ out,
                                                    const float* __restrict__ W4,
                                                    float* __restrict__ z) {
    int tid = threadIdx.x;
    int wave = tid >> 6;
    int lane = tid & 63;
    int lrow = lane & 15;
    int kgrp = lane >> 4;

    int r0 = blockIdx.x * 64 + wave * 16;
    int arow = r0 + lrow;
    if (arow >= NN) arow = NN - 1;

    f32x4 acc[8];
    #pragma unroll
    for (int ct = 0; ct < 8; ct++) acc[ct] = (f32x4){0.f, 0.f, 0.f, 0.f};

    #pragma unroll
    for (int kc = 0; kc < K / 32; kc++) {
        bf16x8 afr = *(const bf16x8*)&A[(size_t)arow * K + kc * 32 + kgrp * 8];
        bf16x8 bfr[8];
        #pragma unroll
        for (int ct = 0; ct < 8; ct++)
            bfr[ct] = *(const bf16x8*)&Wt[(size_t)(ct * 16 + lrow) * K + kc * 32 + kgrp * 8];
        #pragma unroll
        for (int ct = 0; ct < 8; ct++)
            acc[ct] = __builtin_amdgcn_mfma_f32_16x16x32_bf16(afr, bfr[ct], acc[ct], 0, 0, 0);
    }

    // BN scale/shift for this lane's 8 columns (col = ct*16 + lrow)
    float sc[8], sh[8];
    #pragma unroll
    for (int ct = 0; ct < 8; ct++) {
        int col = ct * 16 + lrow;
        float s = g[col] * rsqrtf(v[col] + BN_EPS);
        sc[ct] = s;
        sh[ct] = (bias[col] - m[col]) * s + be[col];
    }

    int rbase = kgrp * 4;   // C layout: row = r0 + rbase + r, col = ct*16 + lrow
    if constexpr (!FUSE_Z) {
        #pragma unroll
        for (int r = 0; r < 4; r++) {
            int row = r0 + rbase + r;
            if (row >= NN) continue;
            #pragma unroll
            for (int ct = 0; ct < 8; ct++) {
                float val = acc[ct][r] * sc[ct] + sh[ct];
                val = fmaxf(val, 0.0f);
                if (res) val += bf2f(res[(size_t)row * HH + ct * 16 + lrow]);
                out[(size_t)row * HH + ct * 16 + lrow] = f2bf(val);
            }
        }
    } else {
        float w4[8];
        #pragma unroll
        for (int ct = 0; ct < 8; ct++) w4[ct] = W4[ct * 16 + lrow];
        #pragma unroll
        for (int r = 0; r < 4; r++) {
            int row = r0 + rbase + r;
            float part = 0.0f;
            if (row < NN) {
                #pragma unroll
                for (int ct = 0; ct < 8; ct++) {
                    float val = acc[ct][r] * sc[ct] + sh[ct];
                    val = fmaxf(val, 0.0f);
                    val += bf2f(res[(size_t)row * HH + ct * 16 + lrow]);
                    part += val * w4[ct];
                }
            }
            #pragma unroll
            for (int off = 1; off < 16; off <<= 1)
                part += __shfl_xor(part, off, 16);
            if (lrow == 0 && row < NN) z[row] = part;
        }
    }
}

// ---------------- final: out[i] = b4 + z[i]*dinv^2 + sum z[src]*w ----------------

__global__ __launch_bounds__(256) void final_kernel(const float* __restrict__ z,
                                                    const int2* __restrict__ csr,
                                                    const int* __restrict__ rowstart,
                                                    const float* __restrict__ dinv,
                                                    const float* __restrict__ b4,
                                                    float* __restrict__ out) {
    int i = blockIdx.x * 256 + threadIdx.x;
    if (i >= NN) return;
    float acc = z[i] * dinv[i] * dinv[i] + b4[0];
    int e0 = rowstart[i], e1 = rowstart[i + 1];
    int e = e0;
    for (; e + 4 <= e1; e += 4) {
        int2 d0 = csr[e + 0];
        int2 d1 = csr[e + 1];
        int2 d2 = csr[e + 2];
        int2 d3 = csr[e + 3];
        float z0 = z[d0.x], z1 = z[d1.x], z2 = z[d2.x], z3 = z[d3.x];
        acc += z0 * __int_as_float(d0.y) + z1 * __int_as_float(d1.y)
             + z2 * __int_as_float(d2.y) + z3 * __int_as_float(d3.y);
    }
    for (; e < e1; e++) {
        int2 ed = csr[e];
        acc += z[ed.x] * __int_as_float(ed.y);
    }
    out[i] = acc;
}

// ---------------- launch ----------------

extern "C" void kernel_launch(void* const* d_in, const int* in_sizes, int n_in,
                              void* d_out, int out_size, void* d_ws, size_t ws_size,
                              hipStream_t stream) {
    const float* x   = (const float*)d_in[0];
    const int*   ei  = (const int*)d_in[1];
    const int*   src = ei;
    const int*   dst = ei + EE;
    const float* W1 = (const float*)d_in[2];
    const float* b1 = (const float*)d_in[3];
    const float* g1 = (const float*)d_in[4];
    const float* be1 = (const float*)d_in[5];
    const float* m1 = (const float*)d_in[6];
    const float* v1 = (const float*)d_in[7];
    const float* W2 = (const float*)d_in[8];
    const float* b2 = (const float*)d_in[9];
    const float* g2 = (const float*)d_in[10];
    const float* be2 = (const float*)d_in[11];
    const float* m2 = (const float*)d_in[12];
    const float* v2 = (const float*)d_in[13];
    const float* W3 = (const float*)d_in[14];
    const float* b3 = (const float*)d_in[15];
    const float* g3 = (const float*)d_in[16];
    const float* be3 = (const float*)d_in[17];
    const float* m3 = (const float*)d_in[18];
    const float* v3 = (const float*)d_in[19];
    const float* W4 = (const float*)d_in[20];
    const float* b4 = (const float*)d_in[21];

    char* wp = (char*)d_ws;
    int*   deg      = (int*)wp;                      wp += (size_t)NN * 4;
    int*   blksum   = (int*)wp;                      wp += 512 * 4;
    int*   rowstart = (int*)wp;                      wp += (size_t)(NN + 1) * 4;
    int*   cursor   = (int*)wp;                      wp += (size_t)NN * 4;
    float* dinv     = (float*)wp;                    wp += (size_t)NN * 4;
    int2*  csr      = (int2*)wp;                     wp += (size_t)EE * 8;
    float* z        = (float*)wp;                    wp += (size_t)NN * 4;
    u16*   wt1      = (u16*)wp;                      wp += (size_t)HH * FIN * 2;
    u16*   wt2      = (u16*)wp;                      wp += (size_t)HH * HH * 2;
    u16*   wt3      = (u16*)wp;                      wp += (size_t)HH * HH * 2;
    u16*   xb       = (u16*)wp;                      wp += (size_t)NN * FIN * 2;
    u16*   x1       = (u16*)wp;                      wp += (size_t)NN * HH * 2;
    u16*   bufA     = (u16*)wp;                      wp += (size_t)NN * HH * 2;
    u16*   bufB     = (u16*)wp;                      wp += (size_t)NN * HH * 2;

    float* outp = (float*)d_out;

    // ---- setup: conversions + CSR build (no hipMemsetAsync — x2bf_zero zeroes deg)
    x2bf_zero_kernel<<<(NN * FIN / 8 + 255) / 256, 256, 0, stream>>>(x, xb, deg);
    wconv_all_kernel<<<(HH * FIN + 2 * HH * HH + 255) / 256, 256, 0, stream>>>(
        W1, W2, W3, wt1, wt2, wt3);
    hist_kernel<<<(EE + 255) / 256, 256, 0, stream>>>(dst, deg);
    scan1_kernel<<<NB, 256, 0, stream>>>(deg, rowstart, blksum, dinv);
    scan2_kernel<<<1, 512, 0, stream>>>(blksum);
    scan3_kernel<<<NB, 256, 0, stream>>>(rowstart, blksum, cursor);
    fill_kernel<<<(EE + 255) / 256, 256, 0, stream>>>(src, dst, dinv, cursor, csr);

    // ---- layer 1: aggregate xb (64 feat), then GEMM 64->128 + BN + ReLU
    agg64_kernel<<<(NN + 15) / 16, 256, 0, stream>>>(xb, csr, rowstart, dinv, bufA);
    gemm_bn_relu<FIN, false><<<(NN + 63) / 64, 256, 0, stream>>>(
        bufA, wt1, b1, g1, be1, m1, v1, nullptr, x1, nullptr, nullptr);

    // ---- layer 2
    agg128_kernel<<<(NN + 7) / 8, 256, 0, stream>>>(x1, csr, rowstart, dinv, bufA);
    gemm_bn_relu<HH, false><<<(NN + 63) / 64, 256, 0, stream>>>(
        bufA, wt2, b2, g2, be2, m2, v2, nullptr, bufB, nullptr, nullptr);

    // ---- layer 3 (+ residual x1) fused with layer-4 GEMV -> z
    agg128_kernel<<<(NN + 7) / 8, 256, 0, stream>>>(bufB, csr, rowstart, dinv, bufA);
    gemm_bn_relu<HH, true><<<(NN + 63) / 64, 256, 0, stream>>>(
        bufA, wt3, b3, g3, be3, m3, v3, x1, nullptr, W4, z);

    // ---- final aggregation of scalars
    final_kernel<<<(NN + 255) / 256, 256, 0, stream>>>(z, csr, rowstart, dinv, b4, outp);
}

// Round 10
// 238.859 us; speedup vs baseline: 1.1990x; 1.0885x over previous
//
#include <hip/hip_runtime.h>

#define NN 100000
#define EE 500000
#define FIN 64
#define HH 128
#define BN_EPS 1e-5f
#define NB ((NN + 255) / 256)   // 391 scan blocks

typedef unsigned short u16;
typedef short bf16x8 __attribute__((ext_vector_type(8)));
typedef float f32x4 __attribute__((ext_vector_type(4)));

__device__ __forceinline__ u16 f2bf(float f) {
    unsigned int u = __float_as_uint(f);
    u = (u + 0x7FFFu + ((u >> 16) & 1u)) >> 16;   // round-to-nearest-even
    return (u16)u;
}
__device__ __forceinline__ float bf2f(u16 u) {
    return __uint_as_float((unsigned int)u << 16);
}

// ---------------- setup: x->bf16, zero deg, all W -> Wt bf16 transposed ----------------

__global__ __launch_bounds__(256) void setup_kernel(const float* __restrict__ x,
                                                    u16* __restrict__ xb,
                                                    int* __restrict__ deg,
                                                    const float* __restrict__ W1,
                                                    const float* __restrict__ W2,
                                                    const float* __restrict__ W3,
                                                    u16* __restrict__ wt1,
                                                    u16* __restrict__ wt2,
                                                    u16* __restrict__ wt3) {
    int i = blockIdx.x * 256 + threadIdx.x;
    if (i < NN) deg[i] = 0;
    if (i < HH * FIN) {
        int n = i / FIN, k = i - n * FIN;
        wt1[i] = f2bf(W1[(size_t)k * HH + n]);
    }
    if (i < HH * HH) {
        int n = i >> 7, k = i & 127;
        wt2[i] = f2bf(W2[(size_t)k * HH + n]);
        wt3[i] = f2bf(W3[(size_t)k * HH + n]);
    }
    if (i < NN * FIN / 8) {
        float4 f0 = ((const float4*)x)[i * 2];
        float4 f1 = ((const float4*)x)[i * 2 + 1];
        uint4 o;
        o.x = (unsigned)f2bf(f0.x) | ((unsigned)f2bf(f0.y) << 16);
        o.y = (unsigned)f2bf(f0.z) | ((unsigned)f2bf(f0.w) << 16);
        o.z = (unsigned)f2bf(f1.x) | ((unsigned)f2bf(f1.y) << 16);
        o.w = (unsigned)f2bf(f1.z) | ((unsigned)f2bf(f1.w) << 16);
        ((uint4*)xb)[i] = o;
    }
}

// ---------------- CSR build ----------------

__global__ __launch_bounds__(256) void hist_kernel(const int* __restrict__ dst,
                                                   int* __restrict__ deg) {
    int e = blockIdx.x * 256 + threadIdx.x;
    if (e < EE) atomicAdd(&deg[dst[e]], 1);
}

// per-block exclusive scan + dinv
__global__ __launch_bounds__(256) void scan1_kernel(const int* __restrict__ deg,
                                                    int* __restrict__ rowstart,
                                                    int* __restrict__ blksum,
                                                    float* __restrict__ dinv) {
    __shared__ int s[256];
    int t = threadIdx.x;
    int i = blockIdx.x * 256 + t;
    int v = (i < NN) ? deg[i] : 0;
    if (i < NN) dinv[i] = rsqrtf((float)v + 1.0f);
    s[t] = v;
    __syncthreads();
    #pragma unroll
    for (int off = 1; off < 256; off <<= 1) {
        int add = (t >= off) ? s[t - off] : 0;
        __syncthreads();
        s[t] += add;
        __syncthreads();
    }
    if (i < NN) rowstart[i] = s[t] - v;
    if (t == 255) blksum[blockIdx.x] = s[255];
}

// scan2+scan3 merged: every block rescans blksum locally (NB=391 <= 512)
__global__ __launch_bounds__(512) void scan23_kernel(int* __restrict__ rowstart,
                                                     const int* __restrict__ blksum,
                                                     int* __restrict__ cursor) {
    __shared__ int s[512];
    __shared__ int ex[512];
    int t = threadIdx.x;
    int vv = (t < NB) ? blksum[t] : 0;
    s[t] = vv;
    __syncthreads();
    #pragma unroll
    for (int off = 1; off < 512; off <<= 1) {
        int add = (t >= off) ? s[t - off] : 0;
        __syncthreads();
        s[t] += add;
        __syncthreads();
    }
    ex[t] = s[t] - vv;
    __syncthreads();
    int i = blockIdx.x * 512 + t;
    if (i < NN) {
        int r = rowstart[i] + ex[i >> 8];
        rowstart[i] = r;
        cursor[i] = r;
    }
    if (i == 0) rowstart[NN] = EE;
}

__global__ __launch_bounds__(256) void fill_kernel(const int* __restrict__ src,
                                                   const int* __restrict__ dst,
                                                   const float* __restrict__ dinv,
                                                   int* __restrict__ cursor,
                                                   int2* __restrict__ csr) {
    int e = blockIdx.x * 256 + threadIdx.x;
    if (e >= EE) return;
    int s = src[e];
    int d = dst[e];
    float nm = dinv[s] * dinv[d];
    int pos = atomicAdd(&cursor[d], 1);
    csr[pos] = make_int2(s, __float_as_int(nm));
}

// ---------------- gather aggregation (bf16 in/out, fp32 accumulate) ----------------
// latency-oriented: sub-wave per node + edge loop unrolled x4 (batched loads)

__global__ __launch_bounds__(256) void agg128_kernel(const u16* __restrict__ x,
                                                     const int2* __restrict__ csr,
                                                     const int* __restrict__ rowstart,
                                                     const float* __restrict__ dinv,
                                                     u16* __restrict__ out) {
    int gid = blockIdx.x * 8 + (threadIdx.x >> 5);
    int lane = threadIdx.x & 31;
    if (gid >= NN) return;
    float sn = dinv[gid];
    sn *= sn;
    const ushort4* xp = (const ushort4*)x;   // row = 32 x ushort4
    ushort4 xv = xp[(size_t)gid * 32 + lane];
    float a0 = bf2f(xv.x) * sn, a1 = bf2f(xv.y) * sn;
    float a2 = bf2f(xv.z) * sn, a3 = bf2f(xv.w) * sn;
    int e0 = rowstart[gid], e1 = rowstart[gid + 1];
    int e = e0;
    for (; e + 4 <= e1; e += 4) {
        int2 d0 = csr[e + 0];
        int2 d1 = csr[e + 1];
        int2 d2 = csr[e + 2];
        int2 d3 = csr[e + 3];
        ushort4 s0 = xp[(size_t)d0.x * 32 + lane];
        ushort4 s1 = xp[(size_t)d1.x * 32 + lane];
        ushort4 s2 = xp[(size_t)d2.x * 32 + lane];
        ushort4 s3 = xp[(size_t)d3.x * 32 + lane];
        float w0 = __int_as_float(d0.y), w1 = __int_as_float(d1.y);
        float w2 = __int_as_float(d2.y), w3 = __int_as_float(d3.y);
        a0 += bf2f(s0.x) * w0; a1 += bf2f(s0.y) * w0; a2 += bf2f(s0.z) * w0; a3 += bf2f(s0.w) * w0;
        a0 += bf2f(s1.x) * w1; a1 += bf2f(s1.y) * w1; a2 += bf2f(s1.z) * w1; a3 += bf2f(s1.w) * w1;
        a0 += bf2f(s2.x) * w2; a1 += bf2f(s2.y) * w2; a2 += bf2f(s2.z) * w2; a3 += bf2f(s2.w) * w2;
        a0 += bf2f(s3.x) * w3; a1 += bf2f(s3.y) * w3; a2 += bf2f(s3.z) * w3; a3 += bf2f(s3.w) * w3;
    }
    for (; e < e1; e++) {
        int2 ed = csr[e];
        float w = __int_as_float(ed.y);
        ushort4 xs = xp[(size_t)ed.x * 32 + lane];
        a0 += bf2f(xs.x) * w; a1 += bf2f(xs.y) * w;
        a2 += bf2f(xs.z) * w; a3 += bf2f(xs.w) * w;
    }
    uint2 o;
    o.x = (unsigned)f2bf(a0) | ((unsigned)f2bf(a1) << 16);
    o.y = (unsigned)f2bf(a2) | ((unsigned)f2bf(a3) << 16);
    ((uint2*)out)[(size_t)gid * 32 + lane] = o;
}

__global__ __launch_bounds__(256) void agg64_kernel(const u16* __restrict__ x,
                                                    const int2* __restrict__ csr,
                                                    const int* __restrict__ rowstart,
                                                    const float* __restrict__ dinv,
                                                    u16* __restrict__ out) {
    int gid = blockIdx.x * 16 + (threadIdx.x >> 4);
    int lane = threadIdx.x & 15;
    if (gid >= NN) return;
    float sn = dinv[gid];
    sn *= sn;
    const ushort4* xp = (const ushort4*)x;   // row = 16 x ushort4
    ushort4 xv = xp[(size_t)gid * 16 + lane];
    float a0 = bf2f(xv.x) * sn, a1 = bf2f(xv.y) * sn;
    float a2 = bf2f(xv.z) * sn, a3 = bf2f(xv.w) * sn;
    int e0 = rowstart[gid], e1 = rowstart[gid + 1];
    int e = e0;
    for (; e + 4 <= e1; e += 4) {
        int2 d0 = csr[e + 0];
        int2 d1 = csr[e + 1];
        int2 d2 = csr[e + 2];
        int2 d3 = csr[e + 3];
        ushort4 s0 = xp[(size_t)d0.x * 16 + lane];
        ushort4 s1 = xp[(size_t)d1.x * 16 + lane];
        ushort4 s2 = xp[(size_t)d2.x * 16 + lane];
        ushort4 s3 = xp[(size_t)d3.x * 16 + lane];
        float w0 = __int_as_float(d0.y), w1 = __int_as_float(d1.y);
        float w2 = __int_as_float(d2.y), w3 = __int_as_float(d3.y);
        a0 += bf2f(s0.x) * w0; a1 += bf2f(s0.y) * w0; a2 += bf2f(s0.z) * w0; a3 += bf2f(s0.w) * w0;
        a0 += bf2f(s1.x) * w1; a1 += bf2f(s1.y) * w1; a2 += bf2f(s1.z) * w1; a3 += bf2f(s1.w) * w1;
        a0 += bf2f(s2.x) * w2; a1 += bf2f(s2.y) * w2; a2 += bf2f(s2.z) * w2; a3 += bf2f(s2.w) * w2;
        a0 += bf2f(s3.x) * w3; a1 += bf2f(s3.y) * w3; a2 += bf2f(s3.z) * w3; a3 += bf2f(s3.w) * w3;
    }
    for (; e < e1; e++) {
        int2 ed = csr[e];
        float w = __int_as_float(ed.y);
        ushort4 xs = xp[(size_t)ed.x * 16 + lane];
        a0 += bf2f(xs.x) * w; a1 += bf2f(xs.y) * w;
        a2 += bf2f(xs.z) * w; a3 += bf2f(xs.w) * w;
    }
    uint2 o;
    o.x = (unsigned)f2bf(a0) | ((unsigned)f2bf(a1) << 16);
    o.y = (unsigned)f2bf(a2) | ((unsigned)f2bf(a3) << 16);
    ((uint2*)out)[(size_t)gid * 16 + lane] = o;
}

// ---------------- MFMA GEMM + bias + BN(eval) + ReLU ----------------
// B-fragments from pre-converted Wt[HH][K] bf16 (L2/L1-hot), no staging barrier.
// Block = 256 thr = 4 waves; wave owns 16 rows (BM=64); grid = ceil(N/64).
// Epilogue via LDS transpose -> coalesced uint4 bf16 stores (no scatter stores).
// MODE 0: store C.  MODE 1: store C and zres[row] = dot(C_row, W4).
// MODE 2: no C store; z[row] = dot(C_row, W4) + zres[row]  (residual folded via zres).

template<int K, int MODE>
__global__ __launch_bounds__(256) void gemm_bn_relu(const u16* __restrict__ A,
                                                    const u16* __restrict__ Wt,
                                                    const float* __restrict__ bias,
                                                    const float* __restrict__ g,
                                                    const float* __restrict__ be,
                                                    const float* __restrict__ m,
                                                    const float* __restrict__ v,
                                                    u16* __restrict__ out,
                                                    const float* __restrict__ W4,
                                                    float* __restrict__ zres,
                                                    float* __restrict__ z) {
    __shared__ u16 Csm[64 * HH];   // 16 KB

    int tid = threadIdx.x;
    int wave = tid >> 6;
    int lane = tid & 63;
    int lrow = lane & 15;
    int kgrp = lane >> 4;

    int blk0 = blockIdx.x * 64;
    int r0 = blk0 + wave * 16;
    int arow = r0 + lrow;
    if (arow >= NN) arow = NN - 1;

    f32x4 acc[8];
    #pragma unroll
    for (int ct = 0; ct < 8; ct++) acc[ct] = (f32x4){0.f, 0.f, 0.f, 0.f};

    #pragma unroll
    for (int kc = 0; kc < K / 32; kc++) {
        bf16x8 afr = *(const bf16x8*)&A[(size_t)arow * K + kc * 32 + kgrp * 8];
        bf16x8 bfr[8];
        #pragma unroll
        for (int ct = 0; ct < 8; ct++)
            bfr[ct] = *(const bf16x8*)&Wt[(size_t)(ct * 16 + lrow) * K + kc * 32 + kgrp * 8];
        #pragma unroll
        for (int ct = 0; ct < 8; ct++)
            acc[ct] = __builtin_amdgcn_mfma_f32_16x16x32_bf16(afr, bfr[ct], acc[ct], 0, 0, 0);
    }

    // BN scale/shift for this lane's 8 columns (col = ct*16 + lrow)
    float sc[8], sh[8];
    #pragma unroll
    for (int ct = 0; ct < 8; ct++) {
        int col = ct * 16 + lrow;
        float s = g[col] * rsqrtf(v[col] + BN_EPS);
        sc[ct] = s;
        sh[ct] = (bias[col] - m[col]) * s + be[col];
    }

    float w4[8];
    if constexpr (MODE >= 1) {
        #pragma unroll
        for (int ct = 0; ct < 8; ct++) w4[ct] = W4[ct * 16 + lrow];
    }

    int rbase = kgrp * 4;   // C layout: row = r0 + rbase + r, col = ct*16 + lrow
    #pragma unroll
    for (int r = 0; r < 4; r++) {
        int row = r0 + rbase + r;
        float part = 0.0f;
        #pragma unroll
        for (int ct = 0; ct < 8; ct++) {
            float val = fmaxf(acc[ct][r] * sc[ct] + sh[ct], 0.0f);
            if constexpr (MODE < 2)
                Csm[(wave * 16 + rbase + r) * HH + ct * 16 + lrow] = f2bf(val);
            if constexpr (MODE >= 1)
                part += val * w4[ct];
        }
        if constexpr (MODE >= 1) {
            #pragma unroll
            for (int off = 1; off < 16; off <<= 1)
                part += __shfl_xor(part, off, 16);
            if (lrow == 0 && row < NN) {
                if constexpr (MODE == 1) zres[row] = part;
                else                     z[row] = part + zres[row];
            }
        }
    }

    if constexpr (MODE < 2) {
        __syncthreads();
        // coalesced writeback: 64 rows x 128 cols bf16 = 16 KB, uint4 per thread x4
        #pragma unroll
        for (int it = 0; it < 4; it++) {
            int id = it * 256 + tid;
            int lr = id >> 4;
            int ch = id & 15;
            int row = blk0 + lr;
            if (row < NN)
                *(uint4*)&out[(size_t)row * HH + ch * 8] =
                    *(const uint4*)&Csm[lr * HH + ch * 8];
        }
    }
}

// ---------------- final: out[i] = b4 + z[i]*dinv^2 + sum z[src]*w ----------------

__global__ __launch_bounds__(256) void final_kernel(const float* __restrict__ z,
                                                    const int2* __restrict__ csr,
                                                    const int* __restrict__ rowstart,
                                                    const float* __restrict__ dinv,
                                                    const float* __restrict__ b4,
                                                    float* __restrict__ out) {
    int i = blockIdx.x * 256 + threadIdx.x;
    if (i >= NN) return;
    float acc = z[i] * dinv[i] * dinv[i] + b4[0];
    int e0 = rowstart[i], e1 = rowstart[i + 1];
    int e = e0;
    for (; e + 4 <= e1; e += 4) {
        int2 d0 = csr[e + 0];
        int2 d1 = csr[e + 1];
        int2 d2 = csr[e + 2];
        int2 d3 = csr[e + 3];
        float z0 = z[d0.x], z1 = z[d1.x], z2 = z[d2.x], z3 = z[d3.x];
        acc += z0 * __int_as_float(d0.y) + z1 * __int_as_float(d1.y)
             + z2 * __int_as_float(d2.y) + z3 * __int_as_float(d3.y);
    }
    for (; e < e1; e++) {
        int2 ed = csr[e];
        acc += z[ed.x] * __int_as_float(ed.y);
    }
    out[i] = acc;
}

// ---------------- launch ----------------

static inline size_t align256(size_t x) { return (x + 255) & ~(size_t)255; }

extern "C" void kernel_launch(void* const* d_in, const int* in_sizes, int n_in,
                              void* d_out, int out_size, void* d_ws, size_t ws_size,
                              hipStream_t stream) {
    const float* x   = (const float*)d_in[0];
    const int*   ei  = (const int*)d_in[1];
    const int*   src = ei;
    const int*   dst = ei + EE;
    const float* W1 = (const float*)d_in[2];
    const float* b1 = (const float*)d_in[3];
    const float* g1 = (const float*)d_in[4];
    const float* be1 = (const float*)d_in[5];
    const float* m1 = (const float*)d_in[6];
    const float* v1 = (const float*)d_in[7];
    const float* W2 = (const float*)d_in[8];
    const float* b2 = (const float*)d_in[9];
    const float* g2 = (const float*)d_in[10];
    const float* be2 = (const float*)d_in[11];
    const float* m2 = (const float*)d_in[12];
    const float* v2 = (const float*)d_in[13];
    const float* W3 = (const float*)d_in[14];
    const float* b3 = (const float*)d_in[15];
    const float* g3 = (const float*)d_in[16];
    const float* be3 = (const float*)d_in[17];
    const float* m3 = (const float*)d_in[18];
    const float* v3 = (const float*)d_in[19];
    const float* W4 = (const float*)d_in[20];
    const float* b4 = (const float*)d_in[21];

    char* wp = (char*)d_ws;
    int*   deg      = (int*)wp;        wp += align256((size_t)NN * 4);
    int*   blksum   = (int*)wp;        wp += align256(512 * 4);
    int*   rowstart = (int*)wp;        wp += align256((size_t)(NN + 1) * 4);
    int*   cursor   = (int*)wp;        wp += align256((size_t)NN * 4);
    float* dinv     = (float*)wp;      wp += align256((size_t)NN * 4);
    int2*  csr      = (int2*)wp;       wp += align256((size_t)EE * 8);
    float* z        = (float*)wp;      wp += align256((size_t)NN * 4);
    float* zres     = (float*)wp;      wp += align256((size_t)NN * 4);
    u16*   wt1      = (u16*)wp;        wp += align256((size_t)HH * FIN * 2);
    u16*   wt2      = (u16*)wp;        wp += align256((size_t)HH * HH * 2);
    u16*   wt3      = (u16*)wp;        wp += align256((size_t)HH * HH * 2);
    u16*   xb       = (u16*)wp;        wp += align256((size_t)NN * FIN * 2);
    u16*   x1       = (u16*)wp;        wp += align256((size_t)NN * HH * 2);
    u16*   x2      = (u16*)wp;         wp += align256((size_t)NN * HH * 2);
    u16*   bufA     = (u16*)wp;        wp += align256((size_t)NN * HH * 2);
    u16*   bufB     = (u16*)wp;        wp += align256((size_t)NN * HH * 2);

    float* outp = (float*)d_out;

    // ---- setup + CSR build (no hipMemsetAsync)
    setup_kernel<<<(NN * FIN / 8 + 255) / 256, 256, 0, stream>>>(
        x, xb, deg, W1, W2, W3, wt1, wt2, wt3);
    hist_kernel<<<(EE + 255) / 256, 256, 0, stream>>>(dst, deg);
    scan1_kernel<<<NB, 256, 0, stream>>>(deg, rowstart, blksum, dinv);
    scan23_kernel<<<(NN + 511) / 512, 512, 0, stream>>>(rowstart, blksum, cursor);
    fill_kernel<<<(EE + 255) / 256, 256, 0, stream>>>(src, dst, dinv, cursor, csr);

    // ---- layer 1: agg(xb) -> bufA; GEMM 64->128 + BN + ReLU -> x1, zres = x1 . W4
    agg64_kernel<<<(NN + 15) / 16, 256, 0, stream>>>(xb, csr, rowstart, dinv, bufA);
    gemm_bn_relu<FIN, 1><<<(NN + 63) / 64, 256, 0, stream>>>(
        bufA, wt1, b1, g1, be1, m1, v1, x1, W4, zres, nullptr);

    // ---- layer 2: agg(x1) -> bufB; GEMM + BN + ReLU -> x2
    agg128_kernel<<<(NN + 7) / 8, 256, 0, stream>>>(x1, csr, rowstart, dinv, bufB);
    gemm_bn_relu<HH, 0><<<(NN + 63) / 64, 256, 0, stream>>>(
        bufB, wt2, b2, g2, be2, m2, v2, x2, nullptr, nullptr, nullptr);

    // ---- layer 3: agg(x2) -> bufA; GEMM + BN + ReLU, fused z = C.W4 + zres
    agg128_kernel<<<(NN + 7) / 8, 256, 0, stream>>>(x2, csr, rowstart, dinv, bufA);
    gemm_bn_relu<HH, 2><<<(NN + 63) / 64, 256, 0, stream>>>(
        bufA, wt3, b3, g3, be3, m3, v3, nullptr, W4, zres, z);

    // ---- final aggregation of scalars
    final_kernel<<<(NN + 255) / 256, 256, 0, stream>>>(z, csr, rowstart, dinv, b4, outp);
}